// Round 8
// baseline (821.021 us; speedup 1.0000x reference)
//
#include <hip/hip_runtime.h>
#include <math.h>

#define BN_EPS 1e-5f

typedef __attribute__((ext_vector_type(8))) short short8;
typedef __attribute__((ext_vector_type(4))) float f32x4;
typedef unsigned int uint_t;

__device__ __forceinline__ float bf2f(unsigned short u) {
  return __builtin_bit_cast(float, ((unsigned)u) << 16);
}
__device__ __forceinline__ unsigned short f2bf(float f) {
  unsigned u = __builtin_bit_cast(unsigned, f);
  unsigned r = (u + 0x7fffu + ((u >> 16) & 1u)) >> 16;
  return (unsigned short)r;
}
// split fp32 -> packed (hi | lo<<16) bf16 pair; hi+lo reproduces x to ~2^-18 rel
__device__ __forceinline__ uint_t packsplit(float x) {
  unsigned short h = f2bf(x);
  unsigned short l = f2bf(x - bf2f(h));
  return (uint_t)h | ((uint_t)l << 16);
}
__device__ __forceinline__ float unpk(uint_t u) {
  return bf2f((unsigned short)(u & 0xffffu)) + bf2f((unsigned short)(u >> 16));
}

// ---------------------------------------------------------------------------
// Edge pass 1: int in-degree + scatter-sum of pos[src] into sum1[dst]
// ---------------------------------------------------------------------------
__global__ void k_deg_sum1(const int* __restrict__ src, const int* __restrict__ dst,
                           const float* __restrict__ pos, int* __restrict__ deg,
                           float* __restrict__ sum1, int E) {
  int e = blockIdx.x * blockDim.x + threadIdx.x;
  if (e >= E) return;
  int s = src[e], d = dst[e];
  atomicAdd(&deg[d], 1);
  atomicAdd(&sum1[d * 3 + 0], pos[s * 3 + 0]);
  atomicAdd(&sum1[d * 3 + 1], pos[s * 3 + 1]);
  atomicAdd(&sum1[d * 3 + 2], pos[s * 3 + 2]);
}

// ---------------------------------------------------------------------------
// Exclusive scan of deg -> rowptr
// ---------------------------------------------------------------------------
__global__ void k_scan1(const int* __restrict__ deg, int* __restrict__ rowptr,
                        int* __restrict__ bsum, int N) {
  __shared__ int part[256];
  int t = threadIdx.x;
  int base = blockIdx.x * 1024;
  int v[4]; int s = 0;
#pragma unroll
  for (int i = 0; i < 4; i++) {
    int idx = base + t * 4 + i;
    v[i] = (idx < N) ? deg[idx] : 0;
    s += v[i];
  }
  part[t] = s;
  __syncthreads();
  for (int off = 1; off < 256; off <<= 1) {
    int x = (t >= off) ? part[t - off] : 0;
    __syncthreads();
    part[t] += x;
    __syncthreads();
  }
  int run = part[t] - s;
#pragma unroll
  for (int i = 0; i < 4; i++) {
    int idx = base + t * 4 + i;
    if (idx < N) rowptr[idx] = run;
    run += v[i];
  }
  if (t == 255) bsum[blockIdx.x] = part[255];
}

__global__ void k_scan2(int* __restrict__ bsum, int nb) {
  if (threadIdx.x == 0 && blockIdx.x == 0) {
    int run = 0;
    for (int i = 0; i < nb; i++) { int v = bsum[i]; bsum[i] = run; run += v; }
  }
}

__global__ void k_scan3(int* __restrict__ rowptr, const int* __restrict__ bsum,
                        int N, int E) {
  int i = blockIdx.x * blockDim.x + threadIdx.x;
  if (i < N) rowptr[i] += bsum[i >> 10];
  else if (i == N) rowptr[N] = E;
}

__global__ void k_fill(const int* __restrict__ src, const int* __restrict__ dst,
                       const int* __restrict__ rowptr, int* __restrict__ fill,
                       int* __restrict__ col, int E) {
  int e = blockIdx.x * blockDim.x + threadIdx.x;
  if (e >= E) return;
  int d = dst[e];
  int p = rowptr[d] + atomicAdd(&fill[d], 1);
  col[p] = src[e];
}

// ---------------------------------------------------------------------------
// SAGE1: x1 = relu(wl @ (sum1/deg) + wr @ pos + b) -> cat[:,0:128] packed
// ---------------------------------------------------------------------------
__global__ void k_sage1(const float* __restrict__ sum1, const int* __restrict__ deg,
                        const float* __restrict__ pos,
                        const float* __restrict__ wl, const float* __restrict__ wr,
                        const float* __restrict__ b,
                        uint_t* __restrict__ cat, int N) {
  int n = blockIdx.x;
  if (n >= N) return;
  int o = threadIdx.x;  // 0..127
  float c = fmaxf((float)deg[n], 1.f);
  float a0 = sum1[n * 3 + 0] / c, a1 = sum1[n * 3 + 1] / c, a2 = sum1[n * 3 + 2] / c;
  float p0 = pos[n * 3 + 0], p1 = pos[n * 3 + 1], p2 = pos[n * 3 + 2];
  float v = b[o] + wl[o * 3 + 0] * a0 + wl[o * 3 + 1] * a1 + wl[o * 3 + 2] * a2
                 + wr[o * 3 + 0] * p0 + wr[o * 3 + 1] * p1 + wr[o * 3 + 2] * p2;
  cat[(size_t)n * 256 + o] = packsplit(fmaxf(v, 0.f));
}

// ---------------------------------------------------------------------------
// Mean-aggregate x1 over incoming edges (packed), wave per node, 4x unroll.
// ---------------------------------------------------------------------------
__global__ void k_agg_x1(const int* __restrict__ rowptr, const int* __restrict__ col,
                         const uint_t* __restrict__ cat,
                         uint_t* __restrict__ agg, int N) {
  int w = (blockIdx.x * blockDim.x + threadIdx.x) >> 6;
  int nw = (gridDim.x * blockDim.x) >> 6;
  int lane = threadIdx.x & 63;
  for (int n = w; n < N; n += nw) {
    int k0 = rowptr[n], k1 = rowptr[n + 1];
    float ax = 0.f, ay = 0.f;
    int k = k0;
    for (; k + 3 < k1; k += 4) {
      int s0 = col[k], s1 = col[k + 1], s2 = col[k + 2], s3 = col[k + 3];
      uint2 v0 = *(const uint2*)&cat[(size_t)s0 * 256 + lane * 2];
      uint2 v1 = *(const uint2*)&cat[(size_t)s1 * 256 + lane * 2];
      uint2 v2 = *(const uint2*)&cat[(size_t)s2 * 256 + lane * 2];
      uint2 v3 = *(const uint2*)&cat[(size_t)s3 * 256 + lane * 2];
      ax += (unpk(v0.x) + unpk(v1.x)) + (unpk(v2.x) + unpk(v3.x));
      ay += (unpk(v0.y) + unpk(v1.y)) + (unpk(v2.y) + unpk(v3.y));
    }
    for (; k < k1; k++) {
      int s = col[k];
      uint2 v = *(const uint2*)&cat[(size_t)s * 256 + lane * 2];
      ax += unpk(v.x);
      ay += unpk(v.y);
    }
    float inv = 1.f / fmaxf((float)(k1 - k0), 1.f);
    uint2 o;
    o.x = packsplit(ax * inv);
    o.y = packsplit(ay * inv);
    *(uint2*)&agg[(size_t)n * 128 + lane * 2] = o;
  }
}

// ---------------------------------------------------------------------------
// Cast/concat fp32 weights -> bf16 hi/lo (separate arrays, GEMM B-operand)
// ---------------------------------------------------------------------------
__global__ void k_castcat(const float* __restrict__ a, const float* __restrict__ b,
                          unsigned short* __restrict__ oH, unsigned short* __restrict__ oL,
                          int K1, int K2, int M) {
  int i = blockIdx.x * blockDim.x + threadIdx.x;
  int K = K1 + K2;
  if (i >= M * K) return;
  int m = i / K, k = i - m * K;
  float v = (k < K1) ? a[m * K1 + k] : b[m * K2 + (k - K1)];
  unsigned short h = f2bf(v);
  oH[i] = h;
  oL[i] = f2bf(v - bf2f(h));
}

// ---------------------------------------------------------------------------
// Split-bf16 MFMA GEMM (fp32-equivalent): C = act(A . W^T + bias).
// A packed (hi|lo per uint), W as separate hi/lo bf16 arrays.
// A.W ~= AhWh + AhWl + AlWh (3 MFMAs / frag pair). Tile 128x128, BK=32,
// 4 waves x (32 rows x 128 cols), mfma_f32_16x16x32_bf16.
// K-loop is software-pipelined: tile k+1's global loads are issued into
// VGPRs before the MFMA block and stored to LDS after the post-MFMA
// barrier — overlapping global latency with compute (R7 exposed it).
// Epilogue: (opt) fused attention dots; LDS-transpose coalesced stores.
// ---------------------------------------------------------------------------
__global__ __launch_bounds__(256) void gemm_split(
    const uint_t* __restrict__ A1, int as1, int K1,
    const uint_t* __restrict__ A2, int as2,
    const unsigned short* __restrict__ WH, const unsigned short* __restrict__ WL,
    const float* __restrict__ bias,
    uint_t* __restrict__ C, int cs, int co, int Nr, int K, int relu,
    const float* __restrict__ asrc, const float* __restrict__ adst,
    float* __restrict__ attn) {
  // one flat LDS pool: 4 staging tiles [128][40] ushort = 40960 B;
  // reused as transpose buffer [128][65] uint = 33280 B.
  __shared__ unsigned short smem[4 * 128 * 40];
  unsigned short (*AsH)[40] = (unsigned short (*)[40])smem;
  unsigned short (*AsL)[40] = (unsigned short (*)[40])(smem + 128 * 40);
  unsigned short (*BsH)[40] = (unsigned short (*)[40])(smem + 2 * 128 * 40);
  unsigned short (*BsL)[40] = (unsigned short (*)[40])(smem + 3 * 128 * 40);
  int tid = threadIdx.x;
  int bm = blockIdx.x, bn = blockIdx.y;
  int wv = tid >> 6, L = tid & 63;
  int m16 = L & 15, quad = L >> 4;
  int rbase = wv * 32;

  // per-thread staging slots (fixed): i in {0,1}
  int row_[2], kc_[2], rg_[2];
  size_t wbase_[2];
#pragma unroll
  for (int i = 0; i < 2; i++) {
    int flat = tid * 2 + i;
    row_[i] = flat >> 2;
    kc_[i] = (flat & 3) * 8;
    rg_[i] = bm * 128 + row_[i];
    wbase_[i] = (size_t)(bn * 128 + row_[i]) * K + kc_[i];
  }

  uint4 pa0[2], pa1[2], pbh[2], pbl[2];

  auto load_tile = [&](int kt) {
    const uint_t* Ap;
    int ast, kl;
    if (kt < K1) { Ap = A1; ast = as1; kl = kt; }
    else         { Ap = A2; ast = as2; kl = kt - K1; }
#pragma unroll
    for (int i = 0; i < 2; i++) {
      uint4 z = {0u, 0u, 0u, 0u};
      pa0[i] = z; pa1[i] = z;
      if (rg_[i] < Nr) {
        const uint_t* ap = &Ap[(size_t)rg_[i] * ast + kl + kc_[i]];
        pa0[i] = *(const uint4*)ap;
        pa1[i] = *(const uint4*)(ap + 4);
      }
      pbh[i] = *(const uint4*)&WH[wbase_[i] + kt];
      pbl[i] = *(const uint4*)&WL[wbase_[i] + kt];
    }
  };
  auto store_tile = [&]() {
#pragma unroll
    for (int i = 0; i < 2; i++) {
      uint4 p0 = pa0[i], p1 = pa1[i];
      uint_t h0 = (p0.x & 0xffffu) | (p0.y << 16), l0 = (p0.x >> 16) | (p0.y & 0xffff0000u);
      uint_t h1 = (p0.z & 0xffffu) | (p0.w << 16), l1 = (p0.z >> 16) | (p0.w & 0xffff0000u);
      uint_t h2 = (p1.x & 0xffffu) | (p1.y << 16), l2 = (p1.x >> 16) | (p1.y & 0xffff0000u);
      uint_t h3 = (p1.z & 0xffffu) | (p1.w << 16), l3 = (p1.z >> 16) | (p1.w & 0xffff0000u);
      *(uint4*)&AsH[row_[i]][kc_[i]] = make_uint4(h0, h1, h2, h3);
      *(uint4*)&AsL[row_[i]][kc_[i]] = make_uint4(l0, l1, l2, l3);
      *(uint4*)&BsH[row_[i]][kc_[i]] = pbh[i];
      *(uint4*)&BsL[row_[i]][kc_[i]] = pbl[i];
    }
  };

  f32x4 acc[2][8];
#pragma unroll
  for (int i = 0; i < 2; i++)
#pragma unroll
    for (int j = 0; j < 8; j++) acc[i][j] = (f32x4){0.f, 0.f, 0.f, 0.f};

  load_tile(0);
  store_tile();

  for (int kt = 0; kt < K; kt += 32) {
    __syncthreads();
    short8 afH[2], afL[2];
#pragma unroll
    for (int rt = 0; rt < 2; rt++) {
      afH[rt] = *(const short8*)&AsH[rbase + rt * 16 + m16][quad * 8];
      afL[rt] = *(const short8*)&AsL[rbase + rt * 16 + m16][quad * 8];
    }
    short8 bH[8], bL[8];
#pragma unroll
    for (int ct = 0; ct < 8; ct++) {
      bH[ct] = *(const short8*)&BsH[ct * 16 + m16][quad * 8];
      bL[ct] = *(const short8*)&BsL[ct * 16 + m16][quad * 8];
    }
    bool more = (kt + 32 < K);
    if (more) load_tile(kt + 32);  // global loads overlap the MFMAs below
#pragma unroll
    for (int ct = 0; ct < 8; ct++) {
#pragma unroll
      for (int rt = 0; rt < 2; rt++) {
        acc[rt][ct] = __builtin_amdgcn_mfma_f32_16x16x32_bf16(afH[rt], bH[ct], acc[rt][ct], 0, 0, 0);
        acc[rt][ct] = __builtin_amdgcn_mfma_f32_16x16x32_bf16(afH[rt], bL[ct], acc[rt][ct], 0, 0, 0);
        acc[rt][ct] = __builtin_amdgcn_mfma_f32_16x16x32_bf16(afL[rt], bH[ct], acc[rt][ct], 0, 0, 0);
      }
    }
    __syncthreads();
    if (more) store_tile();
  }

  // ---- fused attention dots (GAT projection only), from raw acc ----
  if (attn) {
#pragma unroll
    for (int rt = 0; rt < 2; rt++) {
#pragma unroll
      for (int r = 0; r < 4; r++) {
        float a = 0.f, d = 0.f;
#pragma unroll
        for (int ct = 0; ct < 8; ct++) {
          int cg = bn * 128 + ct * 16 + m16;
          float v = acc[rt][ct][r];
          a += v * asrc[cg];
          d += v * adst[cg];
        }
#pragma unroll
        for (int m = 8; m >= 1; m >>= 1) {
          a += __shfl_xor(a, m);
          d += __shfl_xor(d, m);
        }
        if (m16 == 0) {
          int rg = bm * 128 + rbase + rt * 16 + quad * 4 + r;
          if (rg < Nr) {
            attn[rg * 4 + bn] = a;       // a_src, head bn
            attn[rg * 4 + 2 + bn] = d;   // a_dst, head bn
          }
        }
      }
    }
  }

  // ---- epilogue: bias/relu/pack, LDS transpose, coalesced dwordx4 stores ----
  uint_t* T = (uint_t*)smem;  // [128][65]
#pragma unroll
  for (int hc = 0; hc < 2; hc++) {   // column halves of 64
    if (hc) __syncthreads();
#pragma unroll
    for (int rt = 0; rt < 2; rt++) {
#pragma unroll
      for (int ctl = 0; ctl < 4; ctl++) {
        int ct = hc * 4 + ctl;
        int cg = bn * 128 + ct * 16 + m16;
        float bco = bias ? bias[cg] : 0.f;
#pragma unroll
        for (int r = 0; r < 4; r++) {
          int row = rbase + rt * 16 + quad * 4 + r;
          float v = acc[rt][ct][r] + bco;
          if (relu) v = fmaxf(v, 0.f);
          T[row * 65 + ctl * 16 + m16] = packsplit(v);
        }
      }
    }
    __syncthreads();
    int row = tid >> 1;
    int cb = (tid & 1) * 32;
    int rg = bm * 128 + row;
    if (rg < Nr) {
      size_t base = (size_t)rg * cs + co + bn * 128 + hc * 64 + cb;
#pragma unroll
      for (int i2 = 0; i2 < 8; i2++) {
        uint4 q = *(const uint4*)&T[row * 65 + cb + i2 * 4];
        *(uint4*)&C[base + i2 * 4] = q;
      }
    }
  }
}

// ---------------------------------------------------------------------------
// GAT: CSR gather over packed xw, wave per node, 4x edge unroll.
// lanes 0..31 = head0 (ch 0..127), lanes 32..63 = head1 (ch 0..127).
// (softmax shift-invariance: skipping segment-max is mathematically identical)
// ---------------------------------------------------------------------------
__global__ void k_gat_gather(const int* __restrict__ rowptr, const int* __restrict__ col,
                             const uint_t* __restrict__ xw,
                             const float* __restrict__ attn,
                             const float* __restrict__ gb, float* __restrict__ x3g, int N) {
  int w = (blockIdx.x * blockDim.x + threadIdx.x) >> 6;
  int nw = (gridDim.x * blockDim.x) >> 6;
  int lane = threadIdx.x & 63;
  int h = lane >> 5;
  for (int n = w; n < N; n += nw) {
    int k0 = rowptr[n], k1 = rowptr[n + 1];
    float ad = attn[n * 4 + 2 + h];
    float a0 = 0.f, a1 = 0.f, a2 = 0.f, a3 = 0.f, den = 0.f;
    int k = k0;
    for (; k + 3 < k1; k += 4) {
      int s0 = col[k], s1 = col[k + 1], s2 = col[k + 2], s3 = col[k + 3];
      float e0 = attn[s0 * 4 + h] + ad, e1 = attn[s1 * 4 + h] + ad;
      float e2 = attn[s2 * 4 + h] + ad, e3 = attn[s3 * 4 + h] + ad;
      e0 = e0 >= 0.f ? e0 : 0.2f * e0;
      e1 = e1 >= 0.f ? e1 : 0.2f * e1;
      e2 = e2 >= 0.f ? e2 : 0.2f * e2;
      e3 = e3 >= 0.f ? e3 : 0.2f * e3;
      float w0 = expf(e0), w1 = expf(e1), w2 = expf(e2), w3 = expf(e3);
      uint4 x0 = *(const uint4*)&xw[(size_t)s0 * 256 + lane * 4];
      uint4 x1 = *(const uint4*)&xw[(size_t)s1 * 256 + lane * 4];
      uint4 x2 = *(const uint4*)&xw[(size_t)s2 * 256 + lane * 4];
      uint4 x3 = *(const uint4*)&xw[(size_t)s3 * 256 + lane * 4];
      a0 += (w0 * unpk(x0.x) + w1 * unpk(x1.x)) + (w2 * unpk(x2.x) + w3 * unpk(x3.x));
      a1 += (w0 * unpk(x0.y) + w1 * unpk(x1.y)) + (w2 * unpk(x2.y) + w3 * unpk(x3.y));
      a2 += (w0 * unpk(x0.z) + w1 * unpk(x1.z)) + (w2 * unpk(x2.z) + w3 * unpk(x3.z));
      a3 += (w0 * unpk(x0.w) + w1 * unpk(x1.w)) + (w2 * unpk(x2.w) + w3 * unpk(x3.w));
      den += (w0 + w1) + (w2 + w3);
    }
    for (; k < k1; k++) {
      int s = col[k];
      float ea = attn[s * 4 + h] + ad;
      float el = ea >= 0.f ? ea : 0.2f * ea;
      float wgt = expf(el);
      uint4 x = *(const uint4*)&xw[(size_t)s * 256 + lane * 4];
      a0 += wgt * unpk(x.x); a1 += wgt * unpk(x.y);
      a2 += wgt * unpk(x.z); a3 += wgt * unpk(x.w);
      den += wgt;
    }
    {  // self-loop
      float ea = attn[n * 4 + h] + ad;
      float el = ea >= 0.f ? ea : 0.2f * ea;
      float wgt = expf(el);
      uint4 x = *(const uint4*)&xw[(size_t)n * 256 + lane * 4];
      a0 += wgt * unpk(x.x); a1 += wgt * unpk(x.y);
      a2 += wgt * unpk(x.z); a3 += wgt * unpk(x.w);
      den += wgt;
    }
    float invD = 1.f / den;
    float q0 = a0 * invD, q1 = a1 * invD, q2 = a2 * invD, q3 = a3 * invD;
    float p0 = __shfl_xor(q0, 32), p1 = __shfl_xor(q1, 32);
    float p2 = __shfl_xor(q2, 32), p3 = __shfl_xor(q3, 32);
    if (lane < 32) {
      float invc = 1.f / (float)(k1 - k0 + 1);
      float4 g = *(const float4*)&gb[lane * 4];
      float4 r;
      r.x = 0.5f * (q0 + p0) * invc + g.x;
      r.y = 0.5f * (q1 + p1) * invc + g.y;
      r.z = 0.5f * (q2 + p2) * invc + g.z;
      r.w = 0.5f * (q3 + p3) * invc + g.w;
      *(float4*)&x3g[(size_t)n * 128 + lane * 4] = r;
    }
  }
}

// ---------------------------------------------------------------------------
// Global mean pool over sorted batch: run-length accumulate, flush on change
// ---------------------------------------------------------------------------
__global__ void k_pool(const float* __restrict__ x3g, const int* __restrict__ batch,
                       float* __restrict__ zsum, float* __restrict__ zcnt, int N) {
  int t = threadIdx.x;  // 0..127
  int chunk = (N + gridDim.x - 1) / gridDim.x;
  int n0 = blockIdx.x * chunk;
  int n1 = min(N, n0 + chunk);
  if (n0 >= n1) return;
  int cur = batch[n0];
  float acc = 0.f, cacc = 0.f;
  for (int n = n0; n < n1; n++) {
    int b = batch[n];
    if (b != cur) {
      atomicAdd(&zsum[cur * 128 + t], acc);
      if (t == 0) atomicAdd(&zcnt[cur], cacc);
      acc = 0.f; cacc = 0.f; cur = b;
    }
    acc += x3g[(size_t)n * 128 + t];
    cacc += 1.f;
  }
  atomicAdd(&zsum[cur * 128 + t], acc);
  if (t == 0) atomicAdd(&zcnt[cur], cacc);
}

// ---------------------------------------------------------------------------
// Decoder layer, column-parallel: one block (1 wave, Bn=64 threads) per output
// column. Thread r = batch row. BN mean/var via wave shuffle. All fp32.
// If zcntp != null, input rows are zsum and get scaled by 1/max(zcnt,1)
// (fused global-mean-pool normalize — linear, algebraically identical).
// ---------------------------------------------------------------------------
__global__ void dec_col(const float* __restrict__ X, float* __restrict__ Y,
                        const float* __restrict__ W, const float* __restrict__ bias,
                        const float* __restrict__ g, const float* __restrict__ beta,
                        int Ki, int Mo, int Bn, int relu,
                        const float* __restrict__ zcntp) {
  int m = blockIdx.x;
  int r = threadIdx.x;  // 0..Bn-1 (Bn==64)
  float dot = 0.f;
  const float* xr = &X[(size_t)r * Ki];
  const float* wr = &W[(size_t)m * Ki];
  for (int k = 0; k < Ki; k += 4) {
    float4 xv = *(const float4*)&xr[k];
    float4 wv = *(const float4*)&wr[k];
    dot += xv.x * wv.x + xv.y * wv.y + xv.z * wv.z + xv.w * wv.w;
  }
  if (zcntp) dot *= 1.f / fmaxf(zcntp[r], 1.f);
  float acc = dot + bias[m];
  float s = acc;
#pragma unroll
  for (int o = 32; o >= 1; o >>= 1) s += __shfl_xor(s, o);
  float mean = s / (float)Bn;
  float d = acc - mean;
  float v2 = d * d;
#pragma unroll
  for (int o = 32; o >= 1; o >>= 1) v2 += __shfl_xor(v2, o);
  float var = v2 / (float)Bn;
  float y = g[m] * d / sqrtf(var + BN_EPS) + beta[m];
  if (relu) y = fmaxf(y, 0.f);
  Y[(size_t)r * Mo + m] = y;
}

__global__ void k_argmax(const float* __restrict__ z, float* __restrict__ argout,
                         int Bn, int Mo) {
  int r = blockIdx.x * blockDim.x + threadIdx.x;
  if (r >= Bn) return;
  const float* yr = &z[(size_t)r * Mo];
  float best = yr[0];
  int bi = 0;
  for (int j = 1; j < Mo; j++)
    if (yr[j] > best) { best = yr[j]; bi = j; }
  argout[r] = (float)bi;
}

// ---------------------------------------------------------------------------
extern "C" void kernel_launch(void* const* d_in, const int* in_sizes, int n_in,
                              void* d_out, int out_size, void* d_ws, size_t ws_size,
                              hipStream_t stream) {
  const int N = in_sizes[0] / 3;
  const int E = in_sizes[1] / 2;
  const int Bn = out_size / 41;  // z [B,40] + argmax [B]

  const float* pos = (const float*)d_in[0];
  const int* ei = (const int*)d_in[1];
  const int* src = ei;
  const int* dst = ei + E;
  const int* batch = (const int*)d_in[2];
  const float* s1_wl = (const float*)d_in[3];
  const float* s1_wr = (const float*)d_in[4];
  const float* s1_b  = (const float*)d_in[5];
  const float* s2_wl = (const float*)d_in[6];
  const float* s2_wr = (const float*)d_in[7];
  const float* s2_b  = (const float*)d_in[8];
  const float* g_w    = (const float*)d_in[9];
  const float* g_asrc = (const float*)d_in[10];
  const float* g_adst = (const float*)d_in[11];
  const float* g_b    = (const float*)d_in[12];
  const float* d1_w = (const float*)d_in[13];
  const float* d1_b = (const float*)d_in[14];
  const float* bn1_g = (const float*)d_in[15];
  const float* bn1_b = (const float*)d_in[16];
  const float* d2_w = (const float*)d_in[17];
  const float* d2_b = (const float*)d_in[18];
  const float* bn2_g = (const float*)d_in[19];
  const float* bn2_b = (const float*)d_in[20];
  const float* d3_w = (const float*)d_in[21];
  const float* d3_b = (const float*)d_in[22];
  const float* bn3_g = (const float*)d_in[23];
  const float* bn3_b = (const float*)d_in[24];

  size_t Ns = (size_t)N, Es = (size_t)E;
  char* p = (char*)d_ws;
  auto take = [&](size_t bytes) -> char* {
    char* r = p;
    p += (bytes + 255) & ~(size_t)255;
    return r;
  };
  int* deg    = (int*)take(Ns * 4);
  int* fillc  = (int*)take(Ns * 4);
  int* rowptr = (int*)take((Ns + 1) * 4);
  int* bsums  = (int*)take(1024);
  int* col    = (int*)take(Es * 4);
  float* sum1 = (float*)take(3 * Ns * 4);
  float* attn = (float*)take(4 * Ns * 4);
  uint_t* cat = (uint_t*)take(256 * Ns * 4);  // [x1|x2] packed hi|lo
  uint_t* agg = (uint_t*)take(128 * Ns * 4);  // mean-agg packed
  uint_t* xw  = (uint_t*)take(256 * Ns * 4);  // GAT proj packed
  unsigned short* wcH = (unsigned short*)take(128 * 256 * 2); // [s2_wl|s2_wr] hi
  unsigned short* wcL = (unsigned short*)take(128 * 256 * 2);
  unsigned short* gwH = (unsigned short*)take(256 * 256 * 2); // g_w hi
  unsigned short* gwL = (unsigned short*)take(256 * 256 * 2);
  float* zsum  = (float*)take(8192 * 4);
  float* zcnt  = (float*)take(256 * 4);
  float* db1   = (float*)take(16384 * 4);
  float* db2   = (float*)take(8192 * 4);
  // x3g reuses the agg region (agg dead after GEMM1): both 128N x 4B
  float* x3g = (float*)agg;
  float* out = (float*)d_out;

  hipMemsetAsync(deg, 0, Ns * 4, stream);
  hipMemsetAsync(fillc, 0, Ns * 4, stream);
  hipMemsetAsync(sum1, 0, 3 * Ns * 4, stream);
  hipMemsetAsync(zsum, 0, 8192 * 4, stream);
  hipMemsetAsync(zcnt, 0, 256 * 4, stream);

  k_deg_sum1<<<(E + 255) / 256, 256, 0, stream>>>(src, dst, pos, deg, sum1, E);

  int nb = (N + 1023) / 1024;
  k_scan1<<<nb, 256, 0, stream>>>(deg, rowptr, bsums, N);
  k_scan2<<<1, 64, 0, stream>>>(bsums, nb);
  k_scan3<<<(N + 256) / 256, 256, 0, stream>>>(rowptr, bsums, N, E);
  k_fill<<<(E + 255) / 256, 256, 0, stream>>>(src, dst, rowptr, fillc, col, E);

  // weight casts (independent)
  k_castcat<<<(128 * 256 + 255) / 256, 256, 0, stream>>>(s2_wl, s2_wr, wcH, wcL, 128, 128, 128);
  k_castcat<<<(256 * 256 + 255) / 256, 256, 0, stream>>>(g_w, nullptr, gwH, gwL, 256, 0, 256);

  k_sage1<<<N, 128, 0, stream>>>(sum1, deg, pos, s1_wl, s1_wr, s1_b, cat, N);
  k_agg_x1<<<2048, 256, 0, stream>>>(rowptr, col, cat, agg, N);

  // SAGE2: x2 = relu([agg|x1] @ [wl|wr].T + b) -> cat[:,128:256]
  dim3 g2((N + 127) / 128, 1);
  gemm_split<<<g2, 256, 0, stream>>>(agg, 128, 128, cat, 256,
                                     wcH, wcL, s2_b, cat, 256, 128, N, 256, 1,
                                     nullptr, nullptr, nullptr);

  // GAT projection: xw = [x1|x2] @ g_w.T -> xw, with fused attention dots
  dim3 g3((N + 127) / 128, 2);
  gemm_split<<<g3, 256, 0, stream>>>(cat, 256, 256, nullptr, 0,
                                     gwH, gwL, nullptr, xw, 256, 0, N, 256, 0,
                                     g_asrc, g_adst, attn);

  k_gat_gather<<<2048, 256, 0, stream>>>(rowptr, col, xw, attn, g_b, x3g, N);

  k_pool<<<2048, 128, 0, stream>>>(x3g, batch, zsum, zcnt, N);

  // decoder (zmean fused into first layer via zcnt row-scale)
  dec_col<<<256, Bn, 0, stream>>>(zsum, db1, d1_w, d1_b, bn1_g, bn1_b, 128, 256, Bn, 1, zcnt);
  dec_col<<<128, Bn, 0, stream>>>(db1, db2, d2_w, d2_b, bn2_g, bn2_b, 256, 128, Bn, 1, nullptr);
  dec_col<<<40, Bn, 0, stream>>>(db2, out, d3_w, d3_b, bn3_g, bn3_b, 128, 40, Bn, 0, nullptr);
  k_argmax<<<1, 64, 0, stream>>>(out, out + Bn * 40, Bn, 40);
}

// Round 9
// 755.538 us; speedup vs baseline: 1.0867x; 1.0867x over previous
//
#include <hip/hip_runtime.h>
#include <math.h>

#define BN_EPS 1e-5f

typedef __attribute__((ext_vector_type(8))) short short8;
typedef __attribute__((ext_vector_type(4))) float f32x4;
typedef unsigned int uint_t;

__device__ __forceinline__ float bf2f(unsigned short u) {
  return __builtin_bit_cast(float, ((unsigned)u) << 16);
}
__device__ __forceinline__ unsigned short f2bf(float f) {
  unsigned u = __builtin_bit_cast(unsigned, f);
  unsigned r = (u + 0x7fffu + ((u >> 16) & 1u)) >> 16;
  return (unsigned short)r;
}
// split fp32 -> packed (hi | lo<<16) bf16 pair; hi+lo reproduces x to ~2^-18 rel
__device__ __forceinline__ uint_t packsplit(float x) {
  unsigned short h = f2bf(x);
  unsigned short l = f2bf(x - bf2f(h));
  return (uint_t)h | ((uint_t)l << 16);
}
__device__ __forceinline__ float unpk(uint_t u) {
  return bf2f((unsigned short)(u & 0xffffu)) + bf2f((unsigned short)(u >> 16));
}

// ---------------------------------------------------------------------------
// Edge pass 1: int in-degree + scatter-sum of pos[src] into sum1[dst]
// ---------------------------------------------------------------------------
__global__ void k_deg_sum1(const int* __restrict__ src, const int* __restrict__ dst,
                           const float* __restrict__ pos, int* __restrict__ deg,
                           float* __restrict__ sum1, int E) {
  int e = blockIdx.x * blockDim.x + threadIdx.x;
  if (e >= E) return;
  int s = src[e], d = dst[e];
  atomicAdd(&deg[d], 1);
  atomicAdd(&sum1[d * 3 + 0], pos[s * 3 + 0]);
  atomicAdd(&sum1[d * 3 + 1], pos[s * 3 + 1]);
  atomicAdd(&sum1[d * 3 + 2], pos[s * 3 + 2]);
}

// ---------------------------------------------------------------------------
// Exclusive scan of deg -> rowptr
// ---------------------------------------------------------------------------
__global__ void k_scan1(const int* __restrict__ deg, int* __restrict__ rowptr,
                        int* __restrict__ bsum, int N) {
  __shared__ int part[256];
  int t = threadIdx.x;
  int base = blockIdx.x * 1024;
  int v[4]; int s = 0;
#pragma unroll
  for (int i = 0; i < 4; i++) {
    int idx = base + t * 4 + i;
    v[i] = (idx < N) ? deg[idx] : 0;
    s += v[i];
  }
  part[t] = s;
  __syncthreads();
  for (int off = 1; off < 256; off <<= 1) {
    int x = (t >= off) ? part[t - off] : 0;
    __syncthreads();
    part[t] += x;
    __syncthreads();
  }
  int run = part[t] - s;
#pragma unroll
  for (int i = 0; i < 4; i++) {
    int idx = base + t * 4 + i;
    if (idx < N) rowptr[idx] = run;
    run += v[i];
  }
  if (t == 255) bsum[blockIdx.x] = part[255];
}

__global__ void k_scan2(int* __restrict__ bsum, int nb) {
  if (threadIdx.x == 0 && blockIdx.x == 0) {
    int run = 0;
    for (int i = 0; i < nb; i++) { int v = bsum[i]; bsum[i] = run; run += v; }
  }
}

__global__ void k_scan3(int* __restrict__ rowptr, const int* __restrict__ bsum,
                        int N, int E) {
  int i = blockIdx.x * blockDim.x + threadIdx.x;
  if (i < N) rowptr[i] += bsum[i >> 10];
  else if (i == N) rowptr[N] = E;
}

__global__ void k_fill(const int* __restrict__ src, const int* __restrict__ dst,
                       const int* __restrict__ rowptr, int* __restrict__ fill,
                       int* __restrict__ col, int E) {
  int e = blockIdx.x * blockDim.x + threadIdx.x;
  if (e >= E) return;
  int d = dst[e];
  int p = rowptr[d] + atomicAdd(&fill[d], 1);
  col[p] = src[e];
}

// ---------------------------------------------------------------------------
// SAGE1: x1 = relu(wl @ (sum1/deg) + wr @ pos + b) -> cat[:,0:128] packed
// ---------------------------------------------------------------------------
__global__ void k_sage1(const float* __restrict__ sum1, const int* __restrict__ deg,
                        const float* __restrict__ pos,
                        const float* __restrict__ wl, const float* __restrict__ wr,
                        const float* __restrict__ b,
                        uint_t* __restrict__ cat, int N) {
  int n = blockIdx.x;
  if (n >= N) return;
  int o = threadIdx.x;  // 0..127
  float c = fmaxf((float)deg[n], 1.f);
  float a0 = sum1[n * 3 + 0] / c, a1 = sum1[n * 3 + 1] / c, a2 = sum1[n * 3 + 2] / c;
  float p0 = pos[n * 3 + 0], p1 = pos[n * 3 + 1], p2 = pos[n * 3 + 2];
  float v = b[o] + wl[o * 3 + 0] * a0 + wl[o * 3 + 1] * a1 + wl[o * 3 + 2] * a2
                 + wr[o * 3 + 0] * p0 + wr[o * 3 + 1] * p1 + wr[o * 3 + 2] * p2;
  cat[(size_t)n * 256 + o] = packsplit(fmaxf(v, 0.f));
}

// ---------------------------------------------------------------------------
// Mean-aggregate x1 over incoming edges (packed), wave per node, 4x unroll.
// ---------------------------------------------------------------------------
__global__ void k_agg_x1(const int* __restrict__ rowptr, const int* __restrict__ col,
                         const uint_t* __restrict__ cat,
                         uint_t* __restrict__ agg, int N) {
  int w = (blockIdx.x * blockDim.x + threadIdx.x) >> 6;
  int nw = (gridDim.x * blockDim.x) >> 6;
  int lane = threadIdx.x & 63;
  for (int n = w; n < N; n += nw) {
    int k0 = rowptr[n], k1 = rowptr[n + 1];
    float ax = 0.f, ay = 0.f;
    int k = k0;
    for (; k + 3 < k1; k += 4) {
      int s0 = col[k], s1 = col[k + 1], s2 = col[k + 2], s3 = col[k + 3];
      uint2 v0 = *(const uint2*)&cat[(size_t)s0 * 256 + lane * 2];
      uint2 v1 = *(const uint2*)&cat[(size_t)s1 * 256 + lane * 2];
      uint2 v2 = *(const uint2*)&cat[(size_t)s2 * 256 + lane * 2];
      uint2 v3 = *(const uint2*)&cat[(size_t)s3 * 256 + lane * 2];
      ax += (unpk(v0.x) + unpk(v1.x)) + (unpk(v2.x) + unpk(v3.x));
      ay += (unpk(v0.y) + unpk(v1.y)) + (unpk(v2.y) + unpk(v3.y));
    }
    for (; k < k1; k++) {
      int s = col[k];
      uint2 v = *(const uint2*)&cat[(size_t)s * 256 + lane * 2];
      ax += unpk(v.x);
      ay += unpk(v.y);
    }
    float inv = 1.f / fmaxf((float)(k1 - k0), 1.f);
    uint2 o;
    o.x = packsplit(ax * inv);
    o.y = packsplit(ay * inv);
    *(uint2*)&agg[(size_t)n * 128 + lane * 2] = o;
  }
}

// ---------------------------------------------------------------------------
// Cast/concat fp32 weights -> bf16 hi/lo (separate arrays, GEMM B-operand)
// ---------------------------------------------------------------------------
__global__ void k_castcat(const float* __restrict__ a, const float* __restrict__ b,
                          unsigned short* __restrict__ oH, unsigned short* __restrict__ oL,
                          int K1, int K2, int M) {
  int i = blockIdx.x * blockDim.x + threadIdx.x;
  int K = K1 + K2;
  if (i >= M * K) return;
  int m = i / K, k = i - m * K;
  float v = (k < K1) ? a[m * K1 + k] : b[m * K2 + (k - K1)];
  unsigned short h = f2bf(v);
  oH[i] = h;
  oL[i] = f2bf(v - bf2f(h));
}

// ---------------------------------------------------------------------------
// Split-bf16 MFMA GEMM (fp32-equivalent): C = act(A . W^T + bias).
// BARRIER-FREE K-loop: both A (packed hi|lo uints, deinterleaved in regs)
// and W (separate hi/lo bf16) fragments are loaded DIRECTLY from global —
// no LDS staging, no __syncthreads in the loop, so the compiler pipelines
// next-tile loads across MFMAs with plain vmcnt scheduling (R8's register
// prefetch + barriers regressed; this removes the constraint instead).
// W is <=256 KB -> L1/L2-resident across all blocks. Tile 128x128, BK=32,
// 4 waves x (32 rows x 128 cols), mfma_f32_16x16x32_bf16.
// LDS only holds the epilogue transpose buffer (33 KB -> 4 blocks/CU).
// ---------------------------------------------------------------------------
__global__ __launch_bounds__(256, 4) void gemm_split(
    const uint_t* __restrict__ A1, int as1, int K1,
    const uint_t* __restrict__ A2, int as2,
    const unsigned short* __restrict__ WH, const unsigned short* __restrict__ WL,
    const float* __restrict__ bias,
    uint_t* __restrict__ C, int cs, int co, int Nr, int K, int relu,
    const float* __restrict__ asrc, const float* __restrict__ adst,
    float* __restrict__ attn) {
  __shared__ uint_t T[128 * 65];  // epilogue transpose only (33280 B)
  int tid = threadIdx.x;
  int bm = blockIdx.x, bn = blockIdx.y;
  int wv = tid >> 6, L = tid & 63;
  int m16 = L & 15, quad = L >> 4;
  int rbase = wv * 32;

  f32x4 acc[2][8];
#pragma unroll
  for (int i = 0; i < 2; i++)
#pragma unroll
    for (int j = 0; j < 8; j++) acc[i][j] = (f32x4){0.f, 0.f, 0.f, 0.f};

  int rg0 = bm * 128 + rbase + m16;  // rt=0 row; rt=1 row = rg0+16

  for (int kt = 0; kt < K; kt += 32) {
    const uint_t* Ap;
    int ast, kl;
    if (kt < K1) { Ap = A1; ast = as1; kl = kt; }
    else         { Ap = A2; ast = as2; kl = kt - K1; }

    // A fragments: 2 x 32 B contiguous per lane, deinterleave hi/lo in regs
    short8 afH[2], afL[2];
#pragma unroll
    for (int rt = 0; rt < 2; rt++) {
      int rg = rg0 + rt * 16;
      uint4 p0 = {0u, 0u, 0u, 0u}, p1 = {0u, 0u, 0u, 0u};
      if (rg < Nr) {
        const uint_t* ap = &Ap[(size_t)rg * ast + kl + quad * 8];
        p0 = *(const uint4*)ap;
        p1 = *(const uint4*)(ap + 4);
      }
      uint4 hv, lv;
      hv.x = (p0.x & 0xffffu) | (p0.y << 16);  lv.x = (p0.x >> 16) | (p0.y & 0xffff0000u);
      hv.y = (p0.z & 0xffffu) | (p0.w << 16);  lv.y = (p0.z >> 16) | (p0.w & 0xffff0000u);
      hv.z = (p1.x & 0xffffu) | (p1.y << 16);  lv.z = (p1.x >> 16) | (p1.y & 0xffff0000u);
      hv.w = (p1.z & 0xffffu) | (p1.w << 16);  lv.w = (p1.z >> 16) | (p1.w & 0xffff0000u);
      afH[rt] = __builtin_bit_cast(short8, hv);
      afL[rt] = __builtin_bit_cast(short8, lv);
    }

    // B fragments: 16 B contiguous per (ct, hi/lo) per lane, straight from L1/L2
#pragma unroll
    for (int ct = 0; ct < 8; ct++) {
      size_t wb = (size_t)(bn * 128 + ct * 16 + m16) * K + kt + quad * 8;
      short8 bH = *(const short8*)&WH[wb];
      short8 bL = *(const short8*)&WL[wb];
#pragma unroll
      for (int rt = 0; rt < 2; rt++) {
        acc[rt][ct] = __builtin_amdgcn_mfma_f32_16x16x32_bf16(afH[rt], bH, acc[rt][ct], 0, 0, 0);
        acc[rt][ct] = __builtin_amdgcn_mfma_f32_16x16x32_bf16(afH[rt], bL, acc[rt][ct], 0, 0, 0);
        acc[rt][ct] = __builtin_amdgcn_mfma_f32_16x16x32_bf16(afL[rt], bH, acc[rt][ct], 0, 0, 0);
      }
    }
  }

  // ---- fused attention dots (GAT projection only), from raw acc ----
  if (attn) {
#pragma unroll
    for (int rt = 0; rt < 2; rt++) {
#pragma unroll
      for (int r = 0; r < 4; r++) {
        float a = 0.f, d = 0.f;
#pragma unroll
        for (int ct = 0; ct < 8; ct++) {
          int cg = bn * 128 + ct * 16 + m16;
          float v = acc[rt][ct][r];
          a += v * asrc[cg];
          d += v * adst[cg];
        }
#pragma unroll
        for (int m = 8; m >= 1; m >>= 1) {
          a += __shfl_xor(a, m);
          d += __shfl_xor(d, m);
        }
        if (m16 == 0) {
          int rg = bm * 128 + rbase + rt * 16 + quad * 4 + r;
          if (rg < Nr) {
            attn[rg * 4 + bn] = a;       // a_src, head bn
            attn[rg * 4 + 2 + bn] = d;   // a_dst, head bn
          }
        }
      }
    }
  }

  // ---- epilogue: bias/relu/pack, LDS transpose, coalesced dwordx4 stores ----
#pragma unroll
  for (int hc = 0; hc < 2; hc++) {   // column halves of 64
    if (hc) __syncthreads();
#pragma unroll
    for (int rt = 0; rt < 2; rt++) {
#pragma unroll
      for (int ctl = 0; ctl < 4; ctl++) {
        int ct = hc * 4 + ctl;
        int cg = bn * 128 + ct * 16 + m16;
        float bco = bias ? bias[cg] : 0.f;
#pragma unroll
        for (int r = 0; r < 4; r++) {
          int row = rbase + rt * 16 + quad * 4 + r;
          float v = acc[rt][ct][r] + bco;
          if (relu) v = fmaxf(v, 0.f);
          T[row * 65 + ctl * 16 + m16] = packsplit(v);
        }
      }
    }
    __syncthreads();
    int row = tid >> 1;
    int cb = (tid & 1) * 32;
    int rg = bm * 128 + row;
    if (rg < Nr) {
      size_t base = (size_t)rg * cs + co + bn * 128 + hc * 64 + cb;
#pragma unroll
      for (int i2 = 0; i2 < 8; i2++) {
        uint4 q = *(const uint4*)&T[row * 65 + cb + i2 * 4];
        *(uint4*)&C[base + i2 * 4] = q;
      }
    }
  }
}

// ---------------------------------------------------------------------------
// GAT: CSR gather over packed xw, wave per node, 4x edge unroll.
// lanes 0..31 = head0 (ch 0..127), lanes 32..63 = head1 (ch 0..127).
// (softmax shift-invariance: skipping segment-max is mathematically identical)
// ---------------------------------------------------------------------------
__global__ void k_gat_gather(const int* __restrict__ rowptr, const int* __restrict__ col,
                             const uint_t* __restrict__ xw,
                             const float* __restrict__ attn,
                             const float* __restrict__ gb, float* __restrict__ x3g, int N) {
  int w = (blockIdx.x * blockDim.x + threadIdx.x) >> 6;
  int nw = (gridDim.x * blockDim.x) >> 6;
  int lane = threadIdx.x & 63;
  int h = lane >> 5;
  for (int n = w; n < N; n += nw) {
    int k0 = rowptr[n], k1 = rowptr[n + 1];
    float ad = attn[n * 4 + 2 + h];
    float a0 = 0.f, a1 = 0.f, a2 = 0.f, a3 = 0.f, den = 0.f;
    int k = k0;
    for (; k + 3 < k1; k += 4) {
      int s0 = col[k], s1 = col[k + 1], s2 = col[k + 2], s3 = col[k + 3];
      float e0 = attn[s0 * 4 + h] + ad, e1 = attn[s1 * 4 + h] + ad;
      float e2 = attn[s2 * 4 + h] + ad, e3 = attn[s3 * 4 + h] + ad;
      e0 = e0 >= 0.f ? e0 : 0.2f * e0;
      e1 = e1 >= 0.f ? e1 : 0.2f * e1;
      e2 = e2 >= 0.f ? e2 : 0.2f * e2;
      e3 = e3 >= 0.f ? e3 : 0.2f * e3;
      float w0 = expf(e0), w1 = expf(e1), w2 = expf(e2), w3 = expf(e3);
      uint4 x0 = *(const uint4*)&xw[(size_t)s0 * 256 + lane * 4];
      uint4 x1 = *(const uint4*)&xw[(size_t)s1 * 256 + lane * 4];
      uint4 x2 = *(const uint4*)&xw[(size_t)s2 * 256 + lane * 4];
      uint4 x3 = *(const uint4*)&xw[(size_t)s3 * 256 + lane * 4];
      a0 += (w0 * unpk(x0.x) + w1 * unpk(x1.x)) + (w2 * unpk(x2.x) + w3 * unpk(x3.x));
      a1 += (w0 * unpk(x0.y) + w1 * unpk(x1.y)) + (w2 * unpk(x2.y) + w3 * unpk(x3.y));
      a2 += (w0 * unpk(x0.z) + w1 * unpk(x1.z)) + (w2 * unpk(x2.z) + w3 * unpk(x3.z));
      a3 += (w0 * unpk(x0.w) + w1 * unpk(x1.w)) + (w2 * unpk(x2.w) + w3 * unpk(x3.w));
      den += (w0 + w1) + (w2 + w3);
    }
    for (; k < k1; k++) {
      int s = col[k];
      float ea = attn[s * 4 + h] + ad;
      float el = ea >= 0.f ? ea : 0.2f * ea;
      float wgt = expf(el);
      uint4 x = *(const uint4*)&xw[(size_t)s * 256 + lane * 4];
      a0 += wgt * unpk(x.x); a1 += wgt * unpk(x.y);
      a2 += wgt * unpk(x.z); a3 += wgt * unpk(x.w);
      den += wgt;
    }
    {  // self-loop
      float ea = attn[n * 4 + h] + ad;
      float el = ea >= 0.f ? ea : 0.2f * ea;
      float wgt = expf(el);
      uint4 x = *(const uint4*)&xw[(size_t)n * 256 + lane * 4];
      a0 += wgt * unpk(x.x); a1 += wgt * unpk(x.y);
      a2 += wgt * unpk(x.z); a3 += wgt * unpk(x.w);
      den += wgt;
    }
    float invD = 1.f / den;
    float q0 = a0 * invD, q1 = a1 * invD, q2 = a2 * invD, q3 = a3 * invD;
    float p0 = __shfl_xor(q0, 32), p1 = __shfl_xor(q1, 32);
    float p2 = __shfl_xor(q2, 32), p3 = __shfl_xor(q3, 32);
    if (lane < 32) {
      float invc = 1.f / (float)(k1 - k0 + 1);
      float4 g = *(const float4*)&gb[lane * 4];
      float4 r;
      r.x = 0.5f * (q0 + p0) * invc + g.x;
      r.y = 0.5f * (q1 + p1) * invc + g.y;
      r.z = 0.5f * (q2 + p2) * invc + g.z;
      r.w = 0.5f * (q3 + p3) * invc + g.w;
      *(float4*)&x3g[(size_t)n * 128 + lane * 4] = r;
    }
  }
}

// ---------------------------------------------------------------------------
// Global mean pool over sorted batch: run-length accumulate, flush on change
// ---------------------------------------------------------------------------
__global__ void k_pool(const float* __restrict__ x3g, const int* __restrict__ batch,
                       float* __restrict__ zsum, float* __restrict__ zcnt, int N) {
  int t = threadIdx.x;  // 0..127
  int chunk = (N + gridDim.x - 1) / gridDim.x;
  int n0 = blockIdx.x * chunk;
  int n1 = min(N, n0 + chunk);
  if (n0 >= n1) return;
  int cur = batch[n0];
  float acc = 0.f, cacc = 0.f;
  for (int n = n0; n < n1; n++) {
    int b = batch[n];
    if (b != cur) {
      atomicAdd(&zsum[cur * 128 + t], acc);
      if (t == 0) atomicAdd(&zcnt[cur], cacc);
      acc = 0.f; cacc = 0.f; cur = b;
    }
    acc += x3g[(size_t)n * 128 + t];
    cacc += 1.f;
  }
  atomicAdd(&zsum[cur * 128 + t], acc);
  if (t == 0) atomicAdd(&zcnt[cur], cacc);
}

// ---------------------------------------------------------------------------
// Decoder layer, column-parallel: one block (1 wave, Bn=64 threads) per output
// column. Thread r = batch row. BN mean/var via wave shuffle. All fp32.
// If zcntp != null, input rows are zsum and get scaled by 1/max(zcnt,1)
// (fused global-mean-pool normalize — linear, algebraically identical).
// ---------------------------------------------------------------------------
__global__ void dec_col(const float* __restrict__ X, float* __restrict__ Y,
                        const float* __restrict__ W, const float* __restrict__ bias,
                        const float* __restrict__ g, const float* __restrict__ beta,
                        int Ki, int Mo, int Bn, int relu,
                        const float* __restrict__ zcntp) {
  int m = blockIdx.x;
  int r = threadIdx.x;  // 0..Bn-1 (Bn==64)
  float dot = 0.f;
  const float* xr = &X[(size_t)r * Ki];
  const float* wr = &W[(size_t)m * Ki];
  for (int k = 0; k < Ki; k += 4) {
    float4 xv = *(const float4*)&xr[k];
    float4 wv = *(const float4*)&wr[k];
    dot += xv.x * wv.x + xv.y * wv.y + xv.z * wv.z + xv.w * wv.w;
  }
  if (zcntp) dot *= 1.f / fmaxf(zcntp[r], 1.f);
  float acc = dot + bias[m];
  float s = acc;
#pragma unroll
  for (int o = 32; o >= 1; o >>= 1) s += __shfl_xor(s, o);
  float mean = s / (float)Bn;
  float d = acc - mean;
  float v2 = d * d;
#pragma unroll
  for (int o = 32; o >= 1; o >>= 1) v2 += __shfl_xor(v2, o);
  float var = v2 / (float)Bn;
  float y = g[m] * d / sqrtf(var + BN_EPS) + beta[m];
  if (relu) y = fmaxf(y, 0.f);
  Y[(size_t)r * Mo + m] = y;
}

__global__ void k_argmax(const float* __restrict__ z, float* __restrict__ argout,
                         int Bn, int Mo) {
  int r = blockIdx.x * blockDim.x + threadIdx.x;
  if (r >= Bn) return;
  const float* yr = &z[(size_t)r * Mo];
  float best = yr[0];
  int bi = 0;
  for (int j = 1; j < Mo; j++)
    if (yr[j] > best) { best = yr[j]; bi = j; }
  argout[r] = (float)bi;
}

// ---------------------------------------------------------------------------
extern "C" void kernel_launch(void* const* d_in, const int* in_sizes, int n_in,
                              void* d_out, int out_size, void* d_ws, size_t ws_size,
                              hipStream_t stream) {
  const int N = in_sizes[0] / 3;
  const int E = in_sizes[1] / 2;
  const int Bn = out_size / 41;  // z [B,40] + argmax [B]

  const float* pos = (const float*)d_in[0];
  const int* ei = (const int*)d_in[1];
  const int* src = ei;
  const int* dst = ei + E;
  const int* batch = (const int*)d_in[2];
  const float* s1_wl = (const float*)d_in[3];
  const float* s1_wr = (const float*)d_in[4];
  const float* s1_b  = (const float*)d_in[5];
  const float* s2_wl = (const float*)d_in[6];
  const float* s2_wr = (const float*)d_in[7];
  const float* s2_b  = (const float*)d_in[8];
  const float* g_w    = (const float*)d_in[9];
  const float* g_asrc = (const float*)d_in[10];
  const float* g_adst = (const float*)d_in[11];
  const float* g_b    = (const float*)d_in[12];
  const float* d1_w = (const float*)d_in[13];
  const float* d1_b = (const float*)d_in[14];
  const float* bn1_g = (const float*)d_in[15];
  const float* bn1_b = (const float*)d_in[16];
  const float* d2_w = (const float*)d_in[17];
  const float* d2_b = (const float*)d_in[18];
  const float* bn2_g = (const float*)d_in[19];
  const float* bn2_b = (const float*)d_in[20];
  const float* d3_w = (const float*)d_in[21];
  const float* d3_b = (const float*)d_in[22];
  const float* bn3_g = (const float*)d_in[23];
  const float* bn3_b = (const float*)d_in[24];

  size_t Ns = (size_t)N, Es = (size_t)E;
  char* p = (char*)d_ws;
  auto take = [&](size_t bytes) -> char* {
    char* r = p;
    p += (bytes + 255) & ~(size_t)255;
    return r;
  };
  int* deg    = (int*)take(Ns * 4);
  int* fillc  = (int*)take(Ns * 4);
  int* rowptr = (int*)take((Ns + 1) * 4);
  int* bsums  = (int*)take(1024);
  int* col    = (int*)take(Es * 4);
  float* sum1 = (float*)take(3 * Ns * 4);
  float* attn = (float*)take(4 * Ns * 4);
  uint_t* cat = (uint_t*)take(256 * Ns * 4);  // [x1|x2] packed hi|lo
  uint_t* agg = (uint_t*)take(128 * Ns * 4);  // mean-agg packed
  uint_t* xw  = (uint_t*)take(256 * Ns * 4);  // GAT proj packed
  unsigned short* wcH = (unsigned short*)take(128 * 256 * 2); // [s2_wl|s2_wr] hi
  unsigned short* wcL = (unsigned short*)take(128 * 256 * 2);
  unsigned short* gwH = (unsigned short*)take(256 * 256 * 2); // g_w hi
  unsigned short* gwL = (unsigned short*)take(256 * 256 * 2);
  float* zsum  = (float*)take(8192 * 4);
  float* zcnt  = (float*)take(256 * 4);
  float* db1   = (float*)take(16384 * 4);
  float* db2   = (float*)take(8192 * 4);
  // x3g reuses the agg region (agg dead after GEMM1): both 128N x 4B
  float* x3g = (float*)agg;
  float* out = (float*)d_out;

  hipMemsetAsync(deg, 0, Ns * 4, stream);
  hipMemsetAsync(fillc, 0, Ns * 4, stream);
  hipMemsetAsync(sum1, 0, 3 * Ns * 4, stream);
  hipMemsetAsync(zsum, 0, 8192 * 4, stream);
  hipMemsetAsync(zcnt, 0, 256 * 4, stream);

  k_deg_sum1<<<(E + 255) / 256, 256, 0, stream>>>(src, dst, pos, deg, sum1, E);

  int nb = (N + 1023) / 1024;
  k_scan1<<<nb, 256, 0, stream>>>(deg, rowptr, bsums, N);
  k_scan2<<<1, 64, 0, stream>>>(bsums, nb);
  k_scan3<<<(N + 256) / 256, 256, 0, stream>>>(rowptr, bsums, N, E);
  k_fill<<<(E + 255) / 256, 256, 0, stream>>>(src, dst, rowptr, fillc, col, E);

  // weight casts (independent)
  k_castcat<<<(128 * 256 + 255) / 256, 256, 0, stream>>>(s2_wl, s2_wr, wcH, wcL, 128, 128, 128);
  k_castcat<<<(256 * 256 + 255) / 256, 256, 0, stream>>>(g_w, nullptr, gwH, gwL, 256, 0, 256);

  k_sage1<<<N, 128, 0, stream>>>(sum1, deg, pos, s1_wl, s1_wr, s1_b, cat, N);
  k_agg_x1<<<2048, 256, 0, stream>>>(rowptr, col, cat, agg, N);

  // SAGE2: x2 = relu([agg|x1] @ [wl|wr].T + b) -> cat[:,128:256]
  dim3 g2((N + 127) / 128, 1);
  gemm_split<<<g2, 256, 0, stream>>>(agg, 128, 128, cat, 256,
                                     wcH, wcL, s2_b, cat, 256, 128, N, 256, 1,
                                     nullptr, nullptr, nullptr);

  // GAT projection: xw = [x1|x2] @ g_w.T -> xw, with fused attention dots
  dim3 g3((N + 127) / 128, 2);
  gemm_split<<<g3, 256, 0, stream>>>(cat, 256, 256, nullptr, 0,
                                     gwH, gwL, nullptr, xw, 256, 0, N, 256, 0,
                                     g_asrc, g_adst, attn);

  k_gat_gather<<<2048, 256, 0, stream>>>(rowptr, col, xw, attn, g_b, x3g, N);

  k_pool<<<2048, 128, 0, stream>>>(x3g, batch, zsum, zcnt, N);

  // decoder (zmean fused into first layer via zcnt row-scale)
  dec_col<<<256, Bn, 0, stream>>>(zsum, db1, d1_w, d1_b, bn1_g, bn1_b, 128, 256, Bn, 1, zcnt);
  dec_col<<<128, Bn, 0, stream>>>(db1, db2, d2_w, d2_b, bn2_g, bn2_b, 256, 128, Bn, 1, nullptr);
  dec_col<<<40, Bn, 0, stream>>>(db2, out, d3_w, d3_b, bn3_g, bn3_b, 128, 40, Bn, 0, nullptr);
  k_argmax<<<1, 64, 0, stream>>>(out, out + Bn * 40, Bn, 40);
}

// Round 12
// 658.708 us; speedup vs baseline: 1.2464x; 1.1470x over previous
//
#include <hip/hip_runtime.h>
#include <math.h>

#define BN_EPS 1e-5f

typedef __attribute__((ext_vector_type(8))) short short8;
typedef __attribute__((ext_vector_type(4))) float f32x4;
typedef unsigned int uint_t;

__device__ __forceinline__ float bf2f(unsigned short u) {
  return __builtin_bit_cast(float, ((unsigned)u) << 16);
}
__device__ __forceinline__ unsigned short f2bf(float f) {
  unsigned u = __builtin_bit_cast(unsigned, f);
  unsigned r = (u + 0x7fffu + ((u >> 16) & 1u)) >> 16;
  return (unsigned short)r;
}
// split fp32 -> packed (hi | lo<<16) bf16 pair; hi+lo reproduces x to ~2^-18 rel
__device__ __forceinline__ uint_t packsplit(float x) {
  unsigned short h = f2bf(x);
  unsigned short l = f2bf(x - bf2f(h));
  return (uint_t)h | ((uint_t)l << 16);
}
__device__ __forceinline__ float unpk(uint_t u) {
  return bf2f((unsigned short)(u & 0xffffu)) + bf2f((unsigned short)(u >> 16));
}

// ---------------------------------------------------------------------------
// Edge pass 1: int in-degree + scatter-sum of pos[src] into sum1[dst]
// ---------------------------------------------------------------------------
__global__ void k_deg_sum1(const int* __restrict__ src, const int* __restrict__ dst,
                           const float* __restrict__ pos, int* __restrict__ deg,
                           float* __restrict__ sum1, int E) {
  int e = blockIdx.x * blockDim.x + threadIdx.x;
  if (e >= E) return;
  int s = src[e], d = dst[e];
  atomicAdd(&deg[d], 1);
  atomicAdd(&sum1[d * 3 + 0], pos[s * 3 + 0]);
  atomicAdd(&sum1[d * 3 + 1], pos[s * 3 + 1]);
  atomicAdd(&sum1[d * 3 + 2], pos[s * 3 + 2]);
}

// ---------------------------------------------------------------------------
// Exclusive scan of deg -> rowptr
// ---------------------------------------------------------------------------
__global__ void k_scan1(const int* __restrict__ deg, int* __restrict__ rowptr,
                        int* __restrict__ bsum, int N) {
  __shared__ int part[256];
  int t = threadIdx.x;
  int base = blockIdx.x * 1024;
  int v[4]; int s = 0;
#pragma unroll
  for (int i = 0; i < 4; i++) {
    int idx = base + t * 4 + i;
    v[i] = (idx < N) ? deg[idx] : 0;
    s += v[i];
  }
  part[t] = s;
  __syncthreads();
  for (int off = 1; off < 256; off <<= 1) {
    int x = (t >= off) ? part[t - off] : 0;
    __syncthreads();
    part[t] += x;
    __syncthreads();
  }
  int run = part[t] - s;
#pragma unroll
  for (int i = 0; i < 4; i++) {
    int idx = base + t * 4 + i;
    if (idx < N) rowptr[idx] = run;
    run += v[i];
  }
  if (t == 255) bsum[blockIdx.x] = part[255];
}

__global__ void k_scan2(int* __restrict__ bsum, int nb) {
  if (threadIdx.x == 0 && blockIdx.x == 0) {
    int run = 0;
    for (int i = 0; i < nb; i++) { int v = bsum[i]; bsum[i] = run; run += v; }
  }
}

__global__ void k_scan3(int* __restrict__ rowptr, const int* __restrict__ bsum,
                        int N, int E) {
  int i = blockIdx.x * blockDim.x + threadIdx.x;
  if (i < N) rowptr[i] += bsum[i >> 10];
  else if (i == N) rowptr[N] = E;
}

__global__ void k_fill(const int* __restrict__ src, const int* __restrict__ dst,
                       const int* __restrict__ rowptr, int* __restrict__ fill,
                       int* __restrict__ col, int E) {
  int e = blockIdx.x * blockDim.x + threadIdx.x;
  if (e >= E) return;
  int d = dst[e];
  int p = rowptr[d] + atomicAdd(&fill[d], 1);
  col[p] = src[e];
}

// ---------------------------------------------------------------------------
// SAGE1: x1 = relu(wl @ (sum1/deg) + wr @ pos + b) -> cat[:,0:128] packed
// ---------------------------------------------------------------------------
__global__ void k_sage1(const float* __restrict__ sum1, const int* __restrict__ deg,
                        const float* __restrict__ pos,
                        const float* __restrict__ wl, const float* __restrict__ wr,
                        const float* __restrict__ b,
                        uint_t* __restrict__ cat, int N) {
  int n = blockIdx.x;
  if (n >= N) return;
  int o = threadIdx.x;  // 0..127
  float c = fmaxf((float)deg[n], 1.f);
  float a0 = sum1[n * 3 + 0] / c, a1 = sum1[n * 3 + 1] / c, a2 = sum1[n * 3 + 2] / c;
  float p0 = pos[n * 3 + 0], p1 = pos[n * 3 + 1], p2 = pos[n * 3 + 2];
  float v = b[o] + wl[o * 3 + 0] * a0 + wl[o * 3 + 1] * a1 + wl[o * 3 + 2] * a2
                 + wr[o * 3 + 0] * p0 + wr[o * 3 + 1] * p1 + wr[o * 3 + 2] * p2;
  cat[(size_t)n * 256 + o] = packsplit(fmaxf(v, 0.f));
}

// ---------------------------------------------------------------------------
// Mean-aggregate x1 over incoming edges (packed), wave per node, 4x unroll.
// ---------------------------------------------------------------------------
__global__ void k_agg_x1(const int* __restrict__ rowptr, const int* __restrict__ col,
                         const uint_t* __restrict__ cat,
                         uint_t* __restrict__ agg, int N) {
  int w = (blockIdx.x * blockDim.x + threadIdx.x) >> 6;
  int nw = (gridDim.x * blockDim.x) >> 6;
  int lane = threadIdx.x & 63;
  for (int n = w; n < N; n += nw) {
    int k0 = rowptr[n], k1 = rowptr[n + 1];
    float ax = 0.f, ay = 0.f;
    int k = k0;
    for (; k + 3 < k1; k += 4) {
      int s0 = col[k], s1 = col[k + 1], s2 = col[k + 2], s3 = col[k + 3];
      uint2 v0 = *(const uint2*)&cat[(size_t)s0 * 256 + lane * 2];
      uint2 v1 = *(const uint2*)&cat[(size_t)s1 * 256 + lane * 2];
      uint2 v2 = *(const uint2*)&cat[(size_t)s2 * 256 + lane * 2];
      uint2 v3 = *(const uint2*)&cat[(size_t)s3 * 256 + lane * 2];
      ax += (unpk(v0.x) + unpk(v1.x)) + (unpk(v2.x) + unpk(v3.x));
      ay += (unpk(v0.y) + unpk(v1.y)) + (unpk(v2.y) + unpk(v3.y));
    }
    for (; k < k1; k++) {
      int s = col[k];
      uint2 v = *(const uint2*)&cat[(size_t)s * 256 + lane * 2];
      ax += unpk(v.x);
      ay += unpk(v.y);
    }
    float inv = 1.f / fmaxf((float)(k1 - k0), 1.f);
    uint2 o;
    o.x = packsplit(ax * inv);
    o.y = packsplit(ay * inv);
    *(uint2*)&agg[(size_t)n * 128 + lane * 2] = o;
  }
}

// ---------------------------------------------------------------------------
// Cast/concat fp32 weights -> bf16 hi/lo (separate arrays, GEMM B-operand)
// ---------------------------------------------------------------------------
__global__ void k_castcat(const float* __restrict__ a, const float* __restrict__ b,
                          unsigned short* __restrict__ oH, unsigned short* __restrict__ oL,
                          int K1, int K2, int M) {
  int i = blockIdx.x * blockDim.x + threadIdx.x;
  int K = K1 + K2;
  if (i >= M * K) return;
  int m = i / K, k = i - m * K;
  float v = (k < K1) ? a[m * K1 + k] : b[m * K2 + (k - K1)];
  unsigned short h = f2bf(v);
  oH[i] = h;
  oL[i] = f2bf(v - bf2f(h));
}

// ---------------------------------------------------------------------------
// Split-bf16 MFMA GEMM (fp32-equivalent): C = act(A . W^T + bias).
// EXACT R7 structure (the only GEMM variant that passed full timed runs):
// LDS staging with flat = tid*2+i, BK=32, 2 barriers per K-iter.
// A packed (hi|lo per uint), deinterleaved during staging; W separate hi/lo.
// A.W ~= AhWh + AhWl + AlWh (3 MFMAs / frag pair). Tile 128x128,
// 4 waves x (32 rows x 128 cols), mfma_f32_16x16x32_bf16.
// Epilogue: (opt) fused attention dots; LDS-transpose coalesced stores.
// [Do NOT reintroduce: R8 register-prefetch (VGPR blowup), R9 barrier-free
//  direct-global (B-refetch), R11 flat=i*256+tid remap (post-timing diverge).]
// ---------------------------------------------------------------------------
__global__ __launch_bounds__(256) void gemm_split(
    const uint_t* __restrict__ A1, int as1, int K1,
    const uint_t* __restrict__ A2, int as2,
    const unsigned short* __restrict__ WH, const unsigned short* __restrict__ WL,
    const float* __restrict__ bias,
    uint_t* __restrict__ C, int cs, int co, int Nr, int K, int relu,
    const float* __restrict__ asrc, const float* __restrict__ adst,
    float* __restrict__ attn) {
  // one flat LDS pool: 4 staging tiles [128][40] ushort = 40960 B;
  // reused as transpose buffer [128][65] uint = 33280 B.
  __shared__ unsigned short smem[4 * 128 * 40];
  unsigned short (*AsH)[40] = (unsigned short (*)[40])smem;
  unsigned short (*AsL)[40] = (unsigned short (*)[40])(smem + 128 * 40);
  unsigned short (*BsH)[40] = (unsigned short (*)[40])(smem + 2 * 128 * 40);
  unsigned short (*BsL)[40] = (unsigned short (*)[40])(smem + 3 * 128 * 40);
  int tid = threadIdx.x;
  int bm = blockIdx.x, bn = blockIdx.y;
  int wv = tid >> 6, L = tid & 63;
  int m16 = L & 15, quad = L >> 4;
  int rbase = wv * 32;

  f32x4 acc[2][8];
#pragma unroll
  for (int i = 0; i < 2; i++)
#pragma unroll
    for (int j = 0; j < 8; j++) acc[i][j] = (f32x4){0.f, 0.f, 0.f, 0.f};

  for (int kt = 0; kt < K; kt += 32) {
    const uint_t* Ap;
    int ast, kl;
    if (kt < K1) { Ap = A1; ast = as1; kl = kt; }
    else         { Ap = A2; ast = as2; kl = kt - K1; }
#pragma unroll
    for (int i = 0; i < 2; i++) {
      int flat = tid * 2 + i;           // 0..511 (R7-proven mapping)
      int row = flat >> 2;              // 0..127
      int kc = (flat & 3) * 8;          // element offset: 0,8,16,24
      int rg = bm * 128 + row;
      uint4 p0 = {0u, 0u, 0u, 0u}, p1 = {0u, 0u, 0u, 0u};
      if (rg < Nr) {
        const uint_t* ap = &Ap[(size_t)rg * ast + kl + kc];  // kc uints
        p0 = *(const uint4*)ap;
        p1 = *(const uint4*)(ap + 4);
      }
      // deinterleave packed (hi|lo) words into hi-pair / lo-pair words
      uint_t h0 = (p0.x & 0xffffu) | (p0.y << 16), l0 = (p0.x >> 16) | (p0.y & 0xffff0000u);
      uint_t h1 = (p0.z & 0xffffu) | (p0.w << 16), l1 = (p0.z >> 16) | (p0.w & 0xffff0000u);
      uint_t h2 = (p1.x & 0xffffu) | (p1.y << 16), l2 = (p1.x >> 16) | (p1.y & 0xffff0000u);
      uint_t h3 = (p1.z & 0xffffu) | (p1.w << 16), l3 = (p1.z >> 16) | (p1.w & 0xffff0000u);
      *(uint4*)&AsH[row][kc] = make_uint4(h0, h1, h2, h3);   // ushort offset = kc
      *(uint4*)&AsL[row][kc] = make_uint4(l0, l1, l2, l3);
      int ng = bn * 128 + row;
      size_t wb = (size_t)ng * K + kt + kc;                  // ushort offset = kc
      *(uint4*)&BsH[row][kc] = *(const uint4*)&WH[wb];
      *(uint4*)&BsL[row][kc] = *(const uint4*)&WL[wb];
    }
    __syncthreads();
    short8 afH[2], afL[2];
#pragma unroll
    for (int rt = 0; rt < 2; rt++) {
      afH[rt] = *(const short8*)&AsH[rbase + rt * 16 + m16][quad * 8];
      afL[rt] = *(const short8*)&AsL[rbase + rt * 16 + m16][quad * 8];
    }
#pragma unroll
    for (int ct = 0; ct < 8; ct++) {
      short8 bfH = *(const short8*)&BsH[ct * 16 + m16][quad * 8];
      short8 bfL = *(const short8*)&BsL[ct * 16 + m16][quad * 8];
#pragma unroll
      for (int rt = 0; rt < 2; rt++) {
        acc[rt][ct] = __builtin_amdgcn_mfma_f32_16x16x32_bf16(afH[rt], bfH, acc[rt][ct], 0, 0, 0);
        acc[rt][ct] = __builtin_amdgcn_mfma_f32_16x16x32_bf16(afH[rt], bfL, acc[rt][ct], 0, 0, 0);
        acc[rt][ct] = __builtin_amdgcn_mfma_f32_16x16x32_bf16(afL[rt], bfH, acc[rt][ct], 0, 0, 0);
      }
    }
    __syncthreads();
  }

  // ---- fused attention dots (GAT projection only), from raw acc ----
  if (attn) {
#pragma unroll
    for (int rt = 0; rt < 2; rt++) {
#pragma unroll
      for (int r = 0; r < 4; r++) {
        float a = 0.f, d = 0.f;
#pragma unroll
        for (int ct = 0; ct < 8; ct++) {
          int cg = bn * 128 + ct * 16 + m16;
          float v = acc[rt][ct][r];
          a += v * asrc[cg];
          d += v * adst[cg];
        }
#pragma unroll
        for (int m = 8; m >= 1; m >>= 1) {
          a += __shfl_xor(a, m);
          d += __shfl_xor(d, m);
        }
        if (m16 == 0) {
          int rg = bm * 128 + rbase + rt * 16 + quad * 4 + r;
          if (rg < Nr) {
            attn[rg * 4 + bn] = a;       // a_src, head bn
            attn[rg * 4 + 2 + bn] = d;   // a_dst, head bn
          }
        }
      }
    }
  }

  // ---- epilogue: bias/relu/pack, LDS transpose, coalesced dwordx4 stores ----
  uint_t* T = (uint_t*)smem;  // [128][65]
#pragma unroll
  for (int hc = 0; hc < 2; hc++) {   // column halves of 64
    if (hc) __syncthreads();
#pragma unroll
    for (int rt = 0; rt < 2; rt++) {
#pragma unroll
      for (int ctl = 0; ctl < 4; ctl++) {
        int ct = hc * 4 + ctl;
        int cg = bn * 128 + ct * 16 + m16;
        float bco = bias ? bias[cg] : 0.f;
#pragma unroll
        for (int r = 0; r < 4; r++) {
          int row = rbase + rt * 16 + quad * 4 + r;
          float v = acc[rt][ct][r] + bco;
          if (relu) v = fmaxf(v, 0.f);
          T[row * 65 + ctl * 16 + m16] = packsplit(v);
        }
      }
    }
    __syncthreads();
    int row = tid >> 1;
    int cb = (tid & 1) * 32;
    int rg = bm * 128 + row;
    if (rg < Nr) {
      size_t base = (size_t)rg * cs + co + bn * 128 + hc * 64 + cb;
#pragma unroll
      for (int i2 = 0; i2 < 8; i2++) {
        uint4 q = *(const uint4*)&T[row * 65 + cb + i2 * 4];
        *(uint4*)&C[base + i2 * 4] = q;
      }
    }
  }
}

// ---------------------------------------------------------------------------
// GAT: CSR gather over packed xw, wave per node, 4x edge unroll.
// lanes 0..31 = head0 (ch 0..127), lanes 32..63 = head1 (ch 0..127).
// (softmax shift-invariance: skipping segment-max is mathematically identical)
// ---------------------------------------------------------------------------
__global__ void k_gat_gather(const int* __restrict__ rowptr, const int* __restrict__ col,
                             const uint_t* __restrict__ xw,
                             const float* __restrict__ attn,
                             const float* __restrict__ gb, float* __restrict__ x3g, int N) {
  int w = (blockIdx.x * blockDim.x + threadIdx.x) >> 6;
  int nw = (gridDim.x * blockDim.x) >> 6;
  int lane = threadIdx.x & 63;
  int h = lane >> 5;
  for (int n = w; n < N; n += nw) {
    int k0 = rowptr[n], k1 = rowptr[n + 1];
    float ad = attn[n * 4 + 2 + h];
    float a0 = 0.f, a1 = 0.f, a2 = 0.f, a3 = 0.f, den = 0.f;
    int k = k0;
    for (; k + 3 < k1; k += 4) {
      int s0 = col[k], s1 = col[k + 1], s2 = col[k + 2], s3 = col[k + 3];
      float e0 = attn[s0 * 4 + h] + ad, e1 = attn[s1 * 4 + h] + ad;
      float e2 = attn[s2 * 4 + h] + ad, e3 = attn[s3 * 4 + h] + ad;
      e0 = e0 >= 0.f ? e0 : 0.2f * e0;
      e1 = e1 >= 0.f ? e1 : 0.2f * e1;
      e2 = e2 >= 0.f ? e2 : 0.2f * e2;
      e3 = e3 >= 0.f ? e3 : 0.2f * e3;
      float w0 = expf(e0), w1 = expf(e1), w2 = expf(e2), w3 = expf(e3);
      uint4 x0 = *(const uint4*)&xw[(size_t)s0 * 256 + lane * 4];
      uint4 x1 = *(const uint4*)&xw[(size_t)s1 * 256 + lane * 4];
      uint4 x2 = *(const uint4*)&xw[(size_t)s2 * 256 + lane * 4];
      uint4 x3 = *(const uint4*)&xw[(size_t)s3 * 256 + lane * 4];
      a0 += (w0 * unpk(x0.x) + w1 * unpk(x1.x)) + (w2 * unpk(x2.x) + w3 * unpk(x3.x));
      a1 += (w0 * unpk(x0.y) + w1 * unpk(x1.y)) + (w2 * unpk(x2.y) + w3 * unpk(x3.y));
      a2 += (w0 * unpk(x0.z) + w1 * unpk(x1.z)) + (w2 * unpk(x2.z) + w3 * unpk(x3.z));
      a3 += (w0 * unpk(x0.w) + w1 * unpk(x1.w)) + (w2 * unpk(x2.w) + w3 * unpk(x3.w));
      den += (w0 + w1) + (w2 + w3);
    }
    for (; k < k1; k++) {
      int s = col[k];
      float ea = attn[s * 4 + h] + ad;
      float el = ea >= 0.f ? ea : 0.2f * ea;
      float wgt = expf(el);
      uint4 x = *(const uint4*)&xw[(size_t)s * 256 + lane * 4];
      a0 += wgt * unpk(x.x); a1 += wgt * unpk(x.y);
      a2 += wgt * unpk(x.z); a3 += wgt * unpk(x.w);
      den += wgt;
    }
    {  // self-loop
      float ea = attn[n * 4 + h] + ad;
      float el = ea >= 0.f ? ea : 0.2f * ea;
      float wgt = expf(el);
      uint4 x = *(const uint4*)&xw[(size_t)n * 256 + lane * 4];
      a0 += wgt * unpk(x.x); a1 += wgt * unpk(x.y);
      a2 += wgt * unpk(x.z); a3 += wgt * unpk(x.w);
      den += wgt;
    }
    float invD = 1.f / den;
    float q0 = a0 * invD, q1 = a1 * invD, q2 = a2 * invD, q3 = a3 * invD;
    float p0 = __shfl_xor(q0, 32), p1 = __shfl_xor(q1, 32);
    float p2 = __shfl_xor(q2, 32), p3 = __shfl_xor(q3, 32);
    if (lane < 32) {
      float invc = 1.f / (float)(k1 - k0 + 1);
      float4 g = *(const float4*)&gb[lane * 4];
      float4 r;
      r.x = 0.5f * (q0 + p0) * invc + g.x;
      r.y = 0.5f * (q1 + p1) * invc + g.y;
      r.z = 0.5f * (q2 + p2) * invc + g.z;
      r.w = 0.5f * (q3 + p3) * invc + g.w;
      *(float4*)&x3g[(size_t)n * 128 + lane * 4] = r;
    }
  }
}

// ---------------------------------------------------------------------------
// Global mean pool over sorted batch: run-length accumulate, flush on change
// ---------------------------------------------------------------------------
__global__ void k_pool(const float* __restrict__ x3g, const int* __restrict__ batch,
                       float* __restrict__ zsum, float* __restrict__ zcnt, int N) {
  int t = threadIdx.x;  // 0..127
  int chunk = (N + gridDim.x - 1) / gridDim.x;
  int n0 = blockIdx.x * chunk;
  int n1 = min(N, n0 + chunk);
  if (n0 >= n1) return;
  int cur = batch[n0];
  float acc = 0.f, cacc = 0.f;
  for (int n = n0; n < n1; n++) {
    int b = batch[n];
    if (b != cur) {
      atomicAdd(&zsum[cur * 128 + t], acc);
      if (t == 0) atomicAdd(&zcnt[cur], cacc);
      acc = 0.f; cacc = 0.f; cur = b;
    }
    acc += x3g[(size_t)n * 128 + t];
    cacc += 1.f;
  }
  atomicAdd(&zsum[cur * 128 + t], acc);
  if (t == 0) atomicAdd(&zcnt[cur], cacc);
}

// ---------------------------------------------------------------------------
// Decoder layer, column-parallel: one block (1 wave, Bn=64 threads) per output
// column. Thread r = batch row. BN mean/var via wave shuffle. All fp32.
// If zcntp != null, input rows are zsum and get scaled by 1/max(zcnt,1)
// (fused global-mean-pool normalize — linear, algebraically identical).
// ---------------------------------------------------------------------------
__global__ void dec_col(const float* __restrict__ X, float* __restrict__ Y,
                        const float* __restrict__ W, const float* __restrict__ bias,
                        const float* __restrict__ g, const float* __restrict__ beta,
                        int Ki, int Mo, int Bn, int relu,
                        const float* __restrict__ zcntp) {
  int m = blockIdx.x;
  int r = threadIdx.x;  // 0..Bn-1 (Bn==64)
  float dot = 0.f;
  const float* xr = &X[(size_t)r * Ki];
  const float* wr = &W[(size_t)m * Ki];
  for (int k = 0; k < Ki; k += 4) {
    float4 xv = *(const float4*)&xr[k];
    float4 wv = *(const float4*)&wr[k];
    dot += xv.x * wv.x + xv.y * wv.y + xv.z * wv.z + xv.w * wv.w;
  }
  if (zcntp) dot *= 1.f / fmaxf(zcntp[r], 1.f);
  float acc = dot + bias[m];
  float s = acc;
#pragma unroll
  for (int o = 32; o >= 1; o >>= 1) s += __shfl_xor(s, o);
  float mean = s / (float)Bn;
  float d = acc - mean;
  float v2 = d * d;
#pragma unroll
  for (int o = 32; o >= 1; o >>= 1) v2 += __shfl_xor(v2, o);
  float var = v2 / (float)Bn;
  float y = g[m] * d / sqrtf(var + BN_EPS) + beta[m];
  if (relu) y = fmaxf(y, 0.f);
  Y[(size_t)r * Mo + m] = y;
}

__global__ void k_argmax(const float* __restrict__ z, float* __restrict__ argout,
                         int Bn, int Mo) {
  int r = blockIdx.x * blockDim.x + threadIdx.x;
  if (r >= Bn) return;
  const float* yr = &z[(size_t)r * Mo];
  float best = yr[0];
  int bi = 0;
  for (int j = 1; j < Mo; j++)
    if (yr[j] > best) { best = yr[j]; bi = j; }
  argout[r] = (float)bi;
}

// ---------------------------------------------------------------------------
extern "C" void kernel_launch(void* const* d_in, const int* in_sizes, int n_in,
                              void* d_out, int out_size, void* d_ws, size_t ws_size,
                              hipStream_t stream) {
  const int N = in_sizes[0] / 3;
  const int E = in_sizes[1] / 2;
  const int Bn = out_size / 41;  // z [B,40] + argmax [B]

  const float* pos = (const float*)d_in[0];
  const int* ei = (const int*)d_in[1];
  const int* src = ei;
  const int* dst = ei + E;
  const int* batch = (const int*)d_in[2];
  const float* s1_wl = (const float*)d_in[3];
  const float* s1_wr = (const float*)d_in[4];
  const float* s1_b  = (const float*)d_in[5];
  const float* s2_wl = (const float*)d_in[6];
  const float* s2_wr = (const float*)d_in[7];
  const float* s2_b  = (const float*)d_in[8];
  const float* g_w    = (const float*)d_in[9];
  const float* g_asrc = (const float*)d_in[10];
  const float* g_adst = (const float*)d_in[11];
  const float* g_b    = (const float*)d_in[12];
  const float* d1_w = (const float*)d_in[13];
  const float* d1_b = (const float*)d_in[14];
  const float* bn1_g = (const float*)d_in[15];
  const float* bn1_b = (const float*)d_in[16];
  const float* d2_w = (const float*)d_in[17];
  const float* d2_b = (const float*)d_in[18];
  const float* bn2_g = (const float*)d_in[19];
  const float* bn2_b = (const float*)d_in[20];
  const float* d3_w = (const float*)d_in[21];
  const float* d3_b = (const float*)d_in[22];
  const float* bn3_g = (const float*)d_in[23];
  const float* bn3_b = (const float*)d_in[24];

  size_t Ns = (size_t)N, Es = (size_t)E;
  char* p = (char*)d_ws;
  auto take = [&](size_t bytes) -> char* {
    char* r = p;
    p += (bytes + 255) & ~(size_t)255;
    return r;
  };
  int* deg    = (int*)take(Ns * 4);
  int* fillc  = (int*)take(Ns * 4);
  int* rowptr = (int*)take((Ns + 1) * 4);
  int* bsums  = (int*)take(1024);
  int* col    = (int*)take(Es * 4);
  float* sum1 = (float*)take(3 * Ns * 4);
  float* attn = (float*)take(4 * Ns * 4);
  uint_t* cat = (uint_t*)take(256 * Ns * 4);  // [x1|x2] packed hi|lo
  uint_t* agg = (uint_t*)take(128 * Ns * 4);  // mean-agg packed
  uint_t* xw  = (uint_t*)take(256 * Ns * 4);  // GAT proj packed
  unsigned short* wcH = (unsigned short*)take(128 * 256 * 2); // [s2_wl|s2_wr] hi
  unsigned short* wcL = (unsigned short*)take(128 * 256 * 2);
  unsigned short* gwH = (unsigned short*)take(256 * 256 * 2); // g_w hi
  unsigned short* gwL = (unsigned short*)take(256 * 256 * 2);
  float* zsum  = (float*)take(8192 * 4);
  float* zcnt  = (float*)take(256 * 4);
  float* db1   = (float*)take(16384 * 4);
  float* db2   = (float*)take(8192 * 4);
  // x3g reuses the agg region (agg dead after GEMM1): both 128N x 4B
  float* x3g = (float*)agg;
  float* out = (float*)d_out;

  hipMemsetAsync(deg, 0, Ns * 4, stream);
  hipMemsetAsync(fillc, 0, Ns * 4, stream);
  hipMemsetAsync(sum1, 0, 3 * Ns * 4, stream);
  hipMemsetAsync(zsum, 0, 8192 * 4, stream);
  hipMemsetAsync(zcnt, 0, 256 * 4, stream);

  k_deg_sum1<<<(E + 255) / 256, 256, 0, stream>>>(src, dst, pos, deg, sum1, E);

  int nb = (N + 1023) / 1024;
  k_scan1<<<nb, 256, 0, stream>>>(deg, rowptr, bsums, N);
  k_scan2<<<1, 64, 0, stream>>>(bsums, nb);
  k_scan3<<<(N + 256) / 256, 256, 0, stream>>>(rowptr, bsums, N, E);
  k_fill<<<(E + 255) / 256, 256, 0, stream>>>(src, dst, rowptr, fillc, col, E);

  // weight casts (independent)
  k_castcat<<<(128 * 256 + 255) / 256, 256, 0, stream>>>(s2_wl, s2_wr, wcH, wcL, 128, 128, 128);
  k_castcat<<<(256 * 256 + 255) / 256, 256, 0, stream>>>(g_w, nullptr, gwH, gwL, 256, 0, 256);

  k_sage1<<<N, 128, 0, stream>>>(sum1, deg, pos, s1_wl, s1_wr, s1_b, cat, N);
  k_agg_x1<<<2048, 256, 0, stream>>>(rowptr, col, cat, agg, N);

  // SAGE2: x2 = relu([agg|x1] @ [wl|wr].T + b) -> cat[:,128:256]
  dim3 g2((N + 127) / 128, 1);
  gemm_split<<<g2, 256, 0, stream>>>(agg, 128, 128, cat, 256,
                                     wcH, wcL, s2_b, cat, 256, 128, N, 256, 1,
                                     nullptr, nullptr, nullptr);

  // GAT projection: xw = [x1|x2] @ g_w.T -> xw, with fused attention dots
  dim3 g3((N + 127) / 128, 2);
  gemm_split<<<g3, 256, 0, stream>>>(cat, 256, 256, nullptr, 0,
                                     gwH, gwL, nullptr, xw, 256, 0, N, 256, 0,
                                     g_asrc, g_adst, attn);

  k_gat_gather<<<2048, 256, 0, stream>>>(rowptr, col, xw, attn, g_b, x3g, N);

  k_pool<<<2048, 128, 0, stream>>>(x3g, batch, zsum, zcnt, N);

  // decoder (zmean fused into first layer via zcnt row-scale)
  dec_col<<<256, Bn, 0, stream>>>(zsum, db1, d1_w, d1_b, bn1_g, bn1_b, 128, 256, Bn, 1, zcnt);
  dec_col<<<128, Bn, 0, stream>>>(db1, db2, d2_w, d2_b, bn2_g, bn2_b, 256, 128, Bn, 1, nullptr);
  dec_col<<<40, Bn, 0, stream>>>(db2, out, d3_w, d3_b, bn3_g, bn3_b, 128, 40, Bn, 0, nullptr);
  k_argmax<<<1, 64, 0, stream>>>(out, out + Bn * 40, Bn, 40);
}